// Round 1
// baseline (120.100 us; speedup 1.0000x reference)
//
#include <hip/hip_runtime.h>

typedef __bf16 bf16;
typedef __bf16 bf16x4 __attribute__((ext_vector_type(4)));
typedef __bf16 bf16x8 __attribute__((ext_vector_type(8)));
typedef float f32x4 __attribute__((ext_vector_type(4)));

#define T_SEQ 2048
#define CDIM  1024
#define QKV_LD 3072
#define MEM   256

// ---------------- cast f32 -> bf16 (vectorized x4) ----------------
__global__ __launch_bounds__(256) void cast_f32_bf16_kernel(const float* __restrict__ in,
                                                            bf16* __restrict__ out, int n4) {
    int i = blockIdx.x * 256 + threadIdx.x;
    if (i < n4) {
        float4 v = reinterpret_cast<const float4*>(in)[i];
        bf16x4 o = { (bf16)v.x, (bf16)v.y, (bf16)v.z, (bf16)v.w };
        reinterpret_cast<bf16x4*>(out)[i] = o;
    }
}

// ------------- transpose+cast: W[K][N] f32 -> Wt[N][K] bf16 -------------
__global__ __launch_bounds__(256) void transpose_cast_kernel(const float* __restrict__ W,
                                                             bf16* __restrict__ Wt,
                                                             int K, int N) {
    __shared__ float tile[64][65];
    const int n0 = blockIdx.x * 64;
    const int k0 = blockIdx.y * 64;
    const int t  = threadIdx.x;
    const int tr = t >> 4;
    const int tc = (t & 15) * 4;
#pragma unroll
    for (int it = 0; it < 4; ++it) {
        int r = it * 16 + tr;
        float4 v = *reinterpret_cast<const float4*>(&W[(size_t)(k0 + r) * N + n0 + tc]);
        tile[r][tc + 0] = v.x; tile[r][tc + 1] = v.y;
        tile[r][tc + 2] = v.z; tile[r][tc + 3] = v.w;
    }
    __syncthreads();
#pragma unroll
    for (int it = 0; it < 4; ++it) {
        int n = it * 16 + tr;
        bf16x4 o;
#pragma unroll
        for (int j = 0; j < 4; ++j) o[j] = (bf16)tile[tc + j][n];
        *reinterpret_cast<bf16x4*>(&Wt[(size_t)(n0 + n) * K + k0 + tc]) = o;
    }
}

// ------------- GEMM: C[M][N] = A[M][K] * Bt[N][K]^T  (bf16 in, f32 acc) -------------
// 128x128 tile, BK=32, 4 waves (2x2), each wave 64x64 via 4x4 16x16x32 MFMA frags.
template<bool OUT_BF16>
__global__ __launch_bounds__(256) void gemm_bt_kernel(const bf16* __restrict__ A,
                                                      const bf16* __restrict__ Bt,
                                                      bf16* __restrict__ Cb,
                                                      float* __restrict__ Cf,
                                                      int M, int N, int K) {
    __shared__ bf16 As[128 * 32];
    __shared__ bf16 Bs[128 * 32];
    const int t    = threadIdx.x;
    const int lane = t & 63;
    const int w    = t >> 6;
    const int wm   = (w >> 1) * 64;
    const int wn   = (w & 1) * 64;
    const int g    = lane >> 4;
    const int r    = lane & 15;
    const int m0   = blockIdx.y * 128;
    const int n0   = blockIdx.x * 128;

    // staging: 512 chunks of 16B per matrix; thread handles chunks t and t+256
    const int ar0 = t >> 2,          ac0 = (t & 3) * 8;
    const int ar1 = (t + 256) >> 2,  ac1 = ((t + 256) & 3) * 8;

    const f32x4 zero4 = {0.f, 0.f, 0.f, 0.f};
    f32x4 acc[4][4];
#pragma unroll
    for (int i = 0; i < 4; ++i)
#pragma unroll
        for (int j = 0; j < 4; ++j) acc[i][j] = zero4;

    const bf16* Ab = A  + (size_t)m0 * K;
    const bf16* Bb = Bt + (size_t)n0 * K;

    for (int k0 = 0; k0 < K; k0 += 32) {
        bf16x8 av0 = *reinterpret_cast<const bf16x8*>(Ab + (size_t)ar0 * K + k0 + ac0);
        bf16x8 av1 = *reinterpret_cast<const bf16x8*>(Ab + (size_t)ar1 * K + k0 + ac1);
        bf16x8 bv0 = *reinterpret_cast<const bf16x8*>(Bb + (size_t)ar0 * K + k0 + ac0);
        bf16x8 bv1 = *reinterpret_cast<const bf16x8*>(Bb + (size_t)ar1 * K + k0 + ac1);
        __syncthreads();
        *reinterpret_cast<bf16x8*>(&As[ar0 * 32 + ac0]) = av0;
        *reinterpret_cast<bf16x8*>(&As[ar1 * 32 + ac1]) = av1;
        *reinterpret_cast<bf16x8*>(&Bs[ar0 * 32 + ac0]) = bv0;
        *reinterpret_cast<bf16x8*>(&Bs[ar1 * 32 + ac1]) = bv1;
        __syncthreads();
        bf16x8 af[4], bfr[4];
#pragma unroll
        for (int i = 0; i < 4; ++i) {
            af[i]  = *reinterpret_cast<const bf16x8*>(&As[(wm + i * 16 + r) * 32 + g * 8]);
            bfr[i] = *reinterpret_cast<const bf16x8*>(&Bs[(wn + i * 16 + r) * 32 + g * 8]);
        }
#pragma unroll
        for (int i = 0; i < 4; ++i)
#pragma unroll
            for (int j = 0; j < 4; ++j)
                acc[i][j] = __builtin_amdgcn_mfma_f32_16x16x32_bf16(af[i], bfr[j], acc[i][j], 0, 0, 0);
    }

    // epilogue: C/D layout col = lane&15, row = 4*(lane>>4)+e  [verified m89]
#pragma unroll
    for (int i = 0; i < 4; ++i) {
#pragma unroll
        for (int j = 0; j < 4; ++j) {
#pragma unroll
            for (int e = 0; e < 4; ++e) {
                int row = m0 + wm + i * 16 + g * 4 + e;
                int col = n0 + wn + j * 16 + r;
                if constexpr (OUT_BF16) Cb[(size_t)row * N + col] = (bf16)acc[i][j][e];
                else                    Cf[(size_t)row * N + col] = acc[i][j][e];
            }
        }
    }
}

// ------------- banded flash attention -------------
// One wave per (b, h, 16-row q-tile). Swapped QK^T: S^T = mfma(Kfrag, Qfrag)
// so softmax rows live at col = lane&15, and S^T C/D regs feed PV's A operand
// directly with K-slot map kmap(g,j) = (j<4 ? 4g+j : 16+4g+j-4).
__global__ __launch_bounds__(256) void attn_kernel(const bf16* __restrict__ qkv,
                                                   bf16* __restrict__ y) {
    const int wid  = blockIdx.x * 4 + (threadIdx.x >> 6);
    const int lane = threadIdx.x & 63;
    const int bh = wid >> 7;     // 0..31
    const int qt = wid & 127;    // 0..127
    const int b = bh >> 4, h = bh & 15;
    const int q0 = qt * 16;
    const int g = lane >> 4, c = lane & 15;
    const float NEG_INF = -__builtin_inff();

    const bf16* base = qkv + (size_t)b * T_SEQ * QKV_LD;
    const bf16* Qb = base + h * 64;
    const bf16* Kb = base + CDIM + h * 64;
    const bf16* Vb = base + 2 * CDIM + h * 64;
    const int q = q0 + c;

    const bf16x8 qf0 = *reinterpret_cast<const bf16x8*>(Qb + (size_t)q * QKV_LD + g * 8);
    const bf16x8 qf1 = *reinterpret_cast<const bf16x8*>(Qb + (size_t)q * QKV_LD + 32 + g * 8);

    const f32x4 zero4 = {0.f, 0.f, 0.f, 0.f};
    f32x4 o[4];
#pragma unroll
    for (int cb = 0; cb < 4; ++cb) o[cb] = zero4;
    float m_run = NEG_INF, l_run = 0.f;

    const int jstart = (q0 - MEM > 0) ? (q0 - MEM) : 0;
    for (int j0 = jstart; j0 < q0 + 16; j0 += 32) {
        // --- S^T for 32 keys (two 16-key subtiles) ---
        const int kr0 = j0 + c;                                   // <= 2047 always
        int kr1 = j0 + 16 + c; kr1 = kr1 < T_SEQ ? kr1 : T_SEQ - 1; // clamp (masked anyway)
        bf16x8 kf00 = *reinterpret_cast<const bf16x8*>(Kb + (size_t)kr0 * QKV_LD + g * 8);
        bf16x8 kf01 = *reinterpret_cast<const bf16x8*>(Kb + (size_t)kr0 * QKV_LD + 32 + g * 8);
        bf16x8 kf10 = *reinterpret_cast<const bf16x8*>(Kb + (size_t)kr1 * QKV_LD + g * 8);
        bf16x8 kf11 = *reinterpret_cast<const bf16x8*>(Kb + (size_t)kr1 * QKV_LD + 32 + g * 8);
        f32x4 s0 = __builtin_amdgcn_mfma_f32_16x16x32_bf16(kf00, qf0, zero4, 0, 0, 0);
        s0 = __builtin_amdgcn_mfma_f32_16x16x32_bf16(kf01, qf1, s0, 0, 0, 0);
        f32x4 s1 = __builtin_amdgcn_mfma_f32_16x16x32_bf16(kf10, qf0, zero4, 0, 0, 0);
        s1 = __builtin_amdgcn_mfma_f32_16x16x32_bf16(kf11, qf1, s1, 0, 0, 0);

        // --- scale + band mask;  S^T value (lane,e) = S[key=j0+4g+e(+16)][q=c] ---
        float mt = NEG_INF;
#pragma unroll
        for (int e = 0; e < 4; ++e) {
            int k0i = j0 + 4 * g + e;
            int k1i = k0i + 16;
            float v0 = (k0i <= q && k0i >= q - MEM) ? s0[e] * 0.125f : NEG_INF;
            float v1 = (k1i <= q && k1i >= q - MEM) ? s1[e] * 0.125f : NEG_INF;
            s0[e] = v0; s1[e] = v1;
            mt = fmaxf(mt, fmaxf(v0, v1));
        }
        mt = fmaxf(mt, __shfl_xor(mt, 16, 64));
        mt = fmaxf(mt, __shfl_xor(mt, 32, 64));
        const float mnew = fmaxf(m_run, mt);
        const float corr = __expf(m_run - mnew);   // first tile: exp(-inf)=0

        float ps = 0.f;
        bf16x8 pav;
#pragma unroll
        for (int e = 0; e < 4; ++e) {
            float e0 = __expf(s0[e] - mnew);
            float e1 = __expf(s1[e] - mnew);
            ps += e0 + e1;
            pav[e]     = (bf16)e0;
            pav[4 + e] = (bf16)e1;
        }
        ps += __shfl_xor(ps, 16, 64);
        ps += __shfl_xor(ps, 32, 64);
        l_run = l_run * corr + ps;
        m_run = mnew;

        // rescale O: O rows are q-local 4g+e -> fetch that q's corr from lane 4g+e
        float cr[4];
#pragma unroll
        for (int e = 0; e < 4; ++e) cr[e] = __shfl(corr, 4 * g + e, 64);
#pragma unroll
        for (int cb = 0; cb < 4; ++cb) {
            o[cb][0] *= cr[0]; o[cb][1] *= cr[1]; o[cb][2] *= cr[2]; o[cb][3] *= cr[3];
        }

        // --- PV: o[cb] += P(16x32) * V(32x16), same K-slot map as pav ---
#pragma unroll
        for (int cb = 0; cb < 4; ++cb) {
            bf16x8 vf;
#pragma unroll
            for (int jj = 0; jj < 8; ++jj) {
                int kk = (jj < 4) ? (4 * g + jj) : (16 + 4 * g + (jj - 4));
                int vr = j0 + kk; vr = vr < T_SEQ ? vr : T_SEQ - 1;
                vf[jj] = Vb[(size_t)vr * QKV_LD + cb * 16 + c];
            }
            o[cb] = __builtin_amdgcn_mfma_f32_16x16x32_bf16(pav, vf, o[cb], 0, 0, 0);
        }
    }

    float lr[4];
#pragma unroll
    for (int e = 0; e < 4; ++e) lr[e] = __shfl(l_run, 4 * g + e, 64);
#pragma unroll
    for (int cb = 0; cb < 4; ++cb)
#pragma unroll
        for (int e = 0; e < 4; ++e)
            y[(size_t)(b * T_SEQ + q0 + 4 * g + e) * CDIM + h * 64 + cb * 16 + c] =
                (bf16)(o[cb][e] / lr[e]);
}

// ---------------- launch ----------------
extern "C" void kernel_launch(void* const* d_in, const int* in_sizes, int n_in,
                              void* d_out, int out_size, void* d_ws, size_t ws_size,
                              hipStream_t stream) {
    const float* x      = (const float*)d_in[0];
    const float* W_attn = (const float*)d_in[1];
    const float* W_proj = (const float*)d_in[2];
    float* out = (float*)d_out;

    char* ws = (char*)d_ws;
    bf16* xb   = (bf16*)(ws);                  //  4096x1024 bf16 =  8 MiB
    bf16* WaT  = (bf16*)(ws + 8388608);        //  3072x1024 bf16 =  6 MiB
    bf16* WpT  = (bf16*)(ws + 14680064);       //  1024x1024 bf16 =  2 MiB
    bf16* qkv  = (bf16*)(ws + 16777216);       //  4096x3072 bf16 = 24 MiB
    bf16* yatt = (bf16*)(ws + 41943040);       //  4096x1024 bf16 =  8 MiB

    cast_f32_bf16_kernel<<<4096, 256, 0, stream>>>(x, xb, 1048576);
    transpose_cast_kernel<<<dim3(48, 16), 256, 0, stream>>>(W_attn, WaT, 1024, 3072);
    transpose_cast_kernel<<<dim3(16, 16), 256, 0, stream>>>(W_proj, WpT, 1024, 1024);

    gemm_bt_kernel<true><<<dim3(24, 32), 256, 0, stream>>>(xb, WaT, qkv, nullptr, 4096, 3072, 1024);
    attn_kernel<<<1024, 256, 0, stream>>>(qkv, yatt);
    gemm_bt_kernel<false><<<dim3(8, 32), 256, 0, stream>>>(yatt, WpT, nullptr, out, 4096, 1024, 1024);
}